// Round 1
// baseline (1374.725 us; speedup 1.0000x reference)
//
#include <hip/hip_runtime.h>

#define D_DIM 256
#define K_CODES 1024
#define HW 4096                  // H*W
#define BDHW 33554432            // 32*256*64*64
#define N_POS 131072             // 32*64*64

// ---------------------------------------------------------------------------
// Kernel A: enorm[k] = sum_d embed[d][k]^2   (embed is [D, K] row-major)
// ---------------------------------------------------------------------------
__global__ void vq_enorm(const float* __restrict__ embed, float* __restrict__ enorm) {
    int k = blockIdx.x * 256 + threadIdx.x;          // 4 blocks x 256 = 1024
    float s = 0.f;
#pragma unroll 8
    for (int d = 0; d < D_DIM; ++d) {
        float e = embed[(size_t)d * K_CODES + k];
        s = fmaf(e, e, s);
    }
    enorm[k] = s;
}

// ---------------------------------------------------------------------------
// Kernel B: per-position argmin_k ( enorm[k] - 2 * x.e_k )
// block = 256 threads, 32 positions (half of one (b,h) W-row).
// Thread layout: kt = t&31 (k columns, 4 k's each), pt = t>>5 (8 rows x 4 pos).
// X tile staged in LDS as xs[d][p] (lanes of a row broadcast-read same addr).
// ---------------------------------------------------------------------------
__launch_bounds__(256, 4)
__global__ void vq_argmin(const float* __restrict__ input,
                          const float* __restrict__ embed,
                          const float* __restrict__ enorm,
                          float* __restrict__ indf) {
    __shared__ float xs[D_DIM][32];                  // 32 KB
    const int blk = blockIdx.x;                      // 4096 blocks
    const int b  = blk >> 7;
    const int h  = (blk >> 1) & 63;
    const int w0 = (blk & 1) * 32;
    const int t  = threadIdx.x;

    // Stage X: input[b, d, h, w0 + 0..31] for all d. 2048 float4 loads.
    const float* inp = input + (size_t)b * (D_DIM * HW) + h * 64 + w0;
#pragma unroll
    for (int i = 0; i < 8; ++i) {
        int f4 = i * 256 + t;                        // float4 id, d = f4>>3
        int d  = f4 >> 3;
        int w  = (f4 & 7) * 4;
        float4 v = *reinterpret_cast<const float4*>(inp + (size_t)d * HW + w);
        reinterpret_cast<float4*>(xs)[f4] = v;
    }
    __syncthreads();

    const int kt = t & 31;
    const int pt = t >> 5;
    const int pbase = pt * 4;

    float best_s[4];
    int   best_k[4];
#pragma unroll
    for (int p = 0; p < 4; ++p) { best_s[p] = 3.4028235e38f; best_k[p] = 0; }

    for (int kc = 0; kc < 8; ++kc) {
        const int k0 = kc * 128 + kt * 4;
        float acc[4][4];
#pragma unroll
        for (int p = 0; p < 4; ++p)
#pragma unroll
            for (int j = 0; j < 4; ++j) acc[p][j] = 0.f;

        const float* ep = embed + k0;
#pragma unroll 2
        for (int d = 0; d < D_DIM; ++d) {
            float4 ev = *reinterpret_cast<const float4*>(ep + (size_t)d * K_CODES);
            float4 xv = *reinterpret_cast<const float4*>(&xs[d][pbase]);
            float xarr[4] = {xv.x, xv.y, xv.z, xv.w};
            float earr[4] = {ev.x, ev.y, ev.z, ev.w};
#pragma unroll
            for (int p = 0; p < 4; ++p)
#pragma unroll
                for (int j = 0; j < 4; ++j)
                    acc[p][j] = fmaf(xarr[p], earr[j], acc[p][j]);
        }

        float4 en4 = *reinterpret_cast<const float4*>(enorm + k0);
        float en[4] = {en4.x, en4.y, en4.z, en4.w};
#pragma unroll
        for (int p = 0; p < 4; ++p) {
            float s0 = en[0] - 2.f * acc[p][0];
            float s1 = en[1] - 2.f * acc[p][1];
            float s2 = en[2] - 2.f * acc[p][2];
            float s3 = en[3] - 2.f * acc[p][3];
            float ls = s0; int lk = k0;
            if (s1 < ls) { ls = s1; lk = k0 + 1; }   // strict <: keep smallest k
            if (s2 < ls) { ls = s2; lk = k0 + 2; }
            if (s3 < ls) { ls = s3; lk = k0 + 3; }
            // reduce across the 32 lanes of this pos-row (lex-min on (s, k))
#pragma unroll
            for (int m = 16; m >= 1; m >>= 1) {
                float os = __shfl_xor(ls, m, 32);
                int   ok = __shfl_xor(lk, m, 32);
                if (os < ls || (os == ls && ok < lk)) { ls = os; lk = ok; }
            }
            // chunks ascend in k, so strict < keeps the earliest (smallest) k
            if (ls < best_s[p]) { best_s[p] = ls; best_k[p] = lk; }
        }
    }

    // Write indices (as float) via LDS reuse for a coalesced store.
    __syncthreads();
    int* bk = reinterpret_cast<int*>(xs);
    if (kt == 0) {
#pragma unroll
        for (int p = 0; p < 4; ++p) bk[pbase + p] = best_k[p];
    }
    __syncthreads();
    if (t < 32) indf[(size_t)blk * 32 + t] = (float)bk[t];
}

// ---------------------------------------------------------------------------
// Kernel C: out0[b,d,h,w] = out1[b,d,h,w] = embed[d][ ind[b,h,w] ]
// Coalesced float4 writes along w; embed gathers stay L1/L2-hot (1 MB table).
// ---------------------------------------------------------------------------
__global__ void vq_gather(const float* __restrict__ embed,
                          const float* __restrict__ indf,
                          float* __restrict__ out0,
                          float* __restrict__ out1) {
    int gid = blockIdx.x * 256 + threadIdx.x;        // BDHW/4 threads
    int w4   = (gid & 15) * 4;                       // W/4 = 16 float4 per row
    int rest = gid >> 4;                             // (b*256 + d)*64 + h
    int h  = rest & 63;
    int bd = rest >> 6;
    int d  = bd & 255;
    int b  = bd >> 8;
    int n  = (b * 64 + h) * 64 + w4;                 // position index
    float4 fi = *reinterpret_cast<const float4*>(indf + n);
    const float* erow = embed + (size_t)d * K_CODES;
    float4 q;
    q.x = erow[(int)fi.x];
    q.y = erow[(int)fi.y];
    q.z = erow[(int)fi.z];
    q.w = erow[(int)fi.w];
    size_t o = (size_t)gid * 4;                      // == ((b*256+d)*64+h)*64 + w4
    *reinterpret_cast<float4*>(out0 + o) = q;
    *reinterpret_cast<float4*>(out1 + o) = q;
}

// ---------------------------------------------------------------------------
extern "C" void kernel_launch(void* const* d_in, const int* in_sizes, int n_in,
                              void* d_out, int out_size, void* d_ws, size_t ws_size,
                              hipStream_t stream) {
    const float* input = (const float*)d_in[0];      // [32, 256, 64, 64] f32
    const float* embed = (const float*)d_in[1];      // [256, 1024] f32
    float* out0  = (float*)d_out;                    // quantize_with_grad
    float* out1  = out0 + (size_t)BDHW;              // quantize
    float* indf  = out0 + (size_t)2 * BDHW;          // embed_ind (as float)
    float* enorm = (float*)d_ws;                     // 1024 floats scratch

    vq_enorm <<<K_CODES / 256, 256, 0, stream>>>(embed, enorm);
    vq_argmin<<<N_POS / 32,    256, 0, stream>>>(input, embed, enorm, indf);
    vq_gather<<<BDHW / 1024,   256, 0, stream>>>(embed, indf, out0, out1);
}

// Round 2
// 1332.139 us; speedup vs baseline: 1.0320x; 1.0320x over previous
//
#include <hip/hip_runtime.h>

#define D_DIM 256
#define K_CODES 1024
#define HW 4096                  // H*W
#define BDHW 33554432            // 32*256*64*64
#define N_POS 131072             // 32*64*64
#define TAU 1.5f

typedef __attribute__((ext_vector_type(8))) short short8v;
typedef __attribute__((ext_vector_type(4))) float float4v;

__device__ __forceinline__ unsigned short f2bf(float f) {
    unsigned int u = __float_as_uint(f);
    u += 0x7fffu + ((u >> 16) & 1u);     // round-to-nearest-even
    return (unsigned short)(u >> 16);
}

// ---------------------------------------------------------------------------
// Kernel 1: prep — embT[k][d] = bf16(embed[d][k]); enorm[k] = sum_d e^2 (fp32)
// ---------------------------------------------------------------------------
__global__ void vq_prep(const float* __restrict__ embed,
                        unsigned short* __restrict__ embT,
                        float* __restrict__ enorm,
                        int* __restrict__ count) {
    int k = blockIdx.x * 256 + threadIdx.x;          // 4 blocks
    float s = 0.f;
#pragma unroll 8
    for (int d = 0; d < D_DIM; ++d) {
        float e = embed[(size_t)d * K_CODES + k];
        s = fmaf(e, e, s);
        embT[(size_t)k * D_DIM + d] = f2bf(e);
    }
    enorm[k] = s;
    if (k == 0) *count = 0;
}

// ---------------------------------------------------------------------------
// Kernel 2: MFMA approximate distances + argmin with (min1,idx1,min2) tracking
// Block: 256 thr (4 waves, 2x2), 128 positions x all 1024 codes.
// A (x bf16) [128 pos][256 d] in LDS (64 KB, XOR-swizzled), staged once.
// B (embT)  [128 k][64 d] in LDS (16 KB), staged per (nc,dc).
// ---------------------------------------------------------------------------
__launch_bounds__(256, 2)
__global__ void vq_argmin(const float* __restrict__ input,
                          const unsigned short* __restrict__ embT,
                          const float* __restrict__ enorm,
                          float* __restrict__ indf,
                          int* __restrict__ count,
                          int* __restrict__ list) {
    __shared__ __align__(16) char lds[81920];
    char* Als = lds;                 // 64 KB
    char* Bls = lds + 65536;         // 16 KB

    const int t   = threadIdx.x;
    const int blk = blockIdx.x;                      // 1024 blocks
    const int n0  = blk * 128;
    const int b   = n0 >> 12;
    const int h0  = (n0 & 4095) >> 6;                // rows h0, h0+1

    // ---- stage A: input[b, d, h0..h0+1, 0..63] -> bf16 swizzled LDS
    const float* xbase = input + (size_t)b * (D_DIM * HW) + h0 * 64;
#pragma unroll 8
    for (int i = 0; i < 32; ++i) {
        int id = i * 256 + t;                        // 8192 float4
        int d  = id >> 5;
        int p4 = id & 31;
        int hoff = p4 >> 4;
        int w4   = (p4 & 15) << 2;
        float4 v = *reinterpret_cast<const float4*>(xbase + (size_t)d * HW + hoff * 64 + w4);
        int pos = hoff * 64 + w4;
        float vv[4] = {v.x, v.y, v.z, v.w};
#pragma unroll
        for (int j = 0; j < 4; ++j) {
            int r = pos + j;
            int byte = r * 512 + ((((d >> 3)) ^ (r & 7)) << 4) + ((d & 7) << 1);
            *reinterpret_cast<unsigned short*>(Als + byte) = f2bf(vv[j]);
        }
    }
    __syncthreads();

    const int lane = t & 63;
    const int wid  = t >> 6;
    const int wm = wid >> 1, wn = wid & 1;           // wave tile: 64 pos x 64 codes
    const int l15 = lane & 15, l4 = lane >> 4;

    float m1[4][4], m2[4][4];
    int   i1[4][4];
#pragma unroll
    for (int mi = 0; mi < 4; ++mi)
#pragma unroll
        for (int r = 0; r < 4; ++r) { m1[mi][r] = 3.402823466e38f; m2[mi][r] = 3.402823466e38f; i1[mi][r] = 0; }

    for (int nc = 0; nc < 8; ++nc) {
        float4v acc[4][4];
#pragma unroll
        for (int mi = 0; mi < 4; ++mi)
#pragma unroll
            for (int ni = 0; ni < 4; ++ni) acc[mi][ni] = (float4v){0.f, 0.f, 0.f, 0.f};

        for (int dc = 0; dc < 4; ++dc) {
            __syncthreads();                         // previous B readers done
#pragma unroll
            for (int i = 0; i < 4; ++i) {            // stage B 16 KB
                int id = i * 256 + t;                // 1024 x 16B
                int r = id >> 3, slot = id & 7;
                uint4 v = *reinterpret_cast<const uint4*>(
                    embT + ((size_t)(nc * 128 + r)) * D_DIM + dc * 64 + slot * 8);
                *reinterpret_cast<uint4*>(Bls + r * 128 + ((slot ^ (r & 7)) << 4)) = v;
            }
            __syncthreads();

            short8v aF[4][2], bF[4][2];
#pragma unroll
            for (int mi = 0; mi < 4; ++mi)
#pragma unroll
                for (int ks = 0; ks < 2; ++ks) {
                    int r = wm * 64 + mi * 16 + l15;
                    int slot = dc * 8 + ks * 4 + l4;
                    aF[mi][ks] = *reinterpret_cast<const short8v*>(Als + r * 512 + ((slot ^ (r & 7)) << 4));
                }
#pragma unroll
            for (int ni = 0; ni < 4; ++ni)
#pragma unroll
                for (int ks = 0; ks < 2; ++ks) {
                    int r = wn * 64 + ni * 16 + l15;
                    int slot = ks * 4 + l4;
                    bF[ni][ks] = *reinterpret_cast<const short8v*>(Bls + r * 128 + ((slot ^ (r & 7)) << 4));
                }
#pragma unroll
            for (int mi = 0; mi < 4; ++mi)
#pragma unroll
                for (int ni = 0; ni < 4; ++ni) {
                    acc[mi][ni] = __builtin_amdgcn_mfma_f32_16x16x32_bf16(aF[mi][0], bF[ni][0], acc[mi][ni], 0, 0, 0);
                    acc[mi][ni] = __builtin_amdgcn_mfma_f32_16x16x32_bf16(aF[mi][1], bF[ni][1], acc[mi][ni], 0, 0, 0);
                }
        }

        // epilogue for this 128-code chunk: s = enorm - 2*dot, update (m1,i1,m2)
#pragma unroll
        for (int ni = 0; ni < 4; ++ni) {
            int code = nc * 128 + wn * 64 + ni * 16 + l15;
            float en = enorm[code];
#pragma unroll
            for (int mi = 0; mi < 4; ++mi)
#pragma unroll
                for (int r = 0; r < 4; ++r) {
                    float s = fmaf(-2.f, acc[mi][ni][r], en);
                    if (s < m1[mi][r]) { m2[mi][r] = m1[mi][r]; m1[mi][r] = s; i1[mi][r] = code; }
                    else m2[mi][r] = fminf(m2[mi][r], s);
                }
        }
    }

    // butterfly across the 16 column-lanes (lex-min on (val, idx), keep min2)
#pragma unroll
    for (int mi = 0; mi < 4; ++mi)
#pragma unroll
        for (int r = 0; r < 4; ++r) {
            float a1 = m1[mi][r], a2 = m2[mi][r]; int ai = i1[mi][r];
#pragma unroll
            for (int m = 8; m >= 1; m >>= 1) {
                float b1 = __shfl_xor(a1, m, 64);
                float b2 = __shfl_xor(a2, m, 64);
                int   bi = __shfl_xor(ai, m, 64);
                bool take = (b1 < a1) || (b1 == a1 && bi < ai);
                float hi = take ? a1 : b1;
                a1 = take ? b1 : a1;
                ai = take ? bi : ai;
                a2 = fminf(fminf(a2, b2), hi);
            }
            m1[mi][r] = a1; m2[mi][r] = a2; i1[mi][r] = ai;
        }

    __syncthreads();                                 // done reading A; reuse LDS
    float* Lm1 = reinterpret_cast<float*>(Als);      // [2][128]
    float* Lm2 = Lm1 + 256;
    int*   Li1 = reinterpret_cast<int*>(Lm2 + 256);
    if (l15 == 0) {
#pragma unroll
        for (int mi = 0; mi < 4; ++mi)
#pragma unroll
            for (int r = 0; r < 4; ++r) {
                int pos = wm * 64 + mi * 16 + l4 * 4 + r;
                Lm1[wn * 128 + pos] = m1[mi][r];
                Lm2[wn * 128 + pos] = m2[mi][r];
                Li1[wn * 128 + pos] = i1[mi][r];
            }
    }
    __syncthreads();
    if (t < 128) {
        float a1 = Lm1[t], a2 = Lm2[t]; int ai = Li1[t];
        float b1 = Lm1[128 + t], b2 = Lm2[128 + t]; int bi = Li1[128 + t];
        bool take = (b1 < a1) || (b1 == a1 && bi < ai);
        float hi = take ? a1 : b1;
        float f1 = take ? b1 : a1;
        int   fi = take ? bi : ai;
        float f2 = fminf(fminf(a2, b2), hi);
        int n = n0 + t;
        indf[n] = (float)fi;
        if (f2 - f1 < TAU) {                         // near-tie: exact rescan later
            int slot = atomicAdd(count, 1);
            list[slot] = n;
        }
    }
}

// ---------------------------------------------------------------------------
// Kernel 3: exact fp32 rescan for flagged positions (one wave per position)
// ---------------------------------------------------------------------------
__global__ void vq_refine(const float* __restrict__ input,
                          const float* __restrict__ embed,
                          const float* __restrict__ enorm,
                          float* __restrict__ indf,
                          const int* __restrict__ count,
                          const int* __restrict__ list) {
    int gw   = blockIdx.x * 4 + (threadIdx.x >> 6);
    int lane = threadIdx.x & 63;
    int cnt  = *count;
    int nw   = gridDim.x * 4;
    for (int i = gw; i < cnt; i += nw) {
        int n = list[i];
        int b = n >> 12, rem = n & 4095;
        int h = rem >> 6, w = rem & 63;
        const float* xp = input + (size_t)b * (D_DIM * HW) + h * 64 + w;
        const float* ep = embed + lane * 16;
        float acc[16];
#pragma unroll
        for (int j = 0; j < 16; ++j) acc[j] = 0.f;
        for (int d = 0; d < D_DIM; ++d) {
            float xd = xp[(size_t)d * HW];
            const float* er = ep + (size_t)d * K_CODES;
            float4 e0 = *reinterpret_cast<const float4*>(er);
            float4 e1 = *reinterpret_cast<const float4*>(er + 4);
            float4 e2 = *reinterpret_cast<const float4*>(er + 8);
            float4 e3 = *reinterpret_cast<const float4*>(er + 12);
            float ea[16] = {e0.x, e0.y, e0.z, e0.w, e1.x, e1.y, e1.z, e1.w,
                            e2.x, e2.y, e2.z, e2.w, e3.x, e3.y, e3.z, e3.w};
#pragma unroll
            for (int j = 0; j < 16; ++j) acc[j] = fmaf(xd, ea[j], acc[j]);
        }
        float bs = 3.402823466e38f; int bk = 0;
#pragma unroll
        for (int j = 0; j < 16; ++j) {
            float s = fmaf(-2.f, acc[j], enorm[lane * 16 + j]);
            if (s < bs) { bs = s; bk = lane * 16 + j; }
        }
#pragma unroll
        for (int m = 32; m >= 1; m >>= 1) {
            float os = __shfl_xor(bs, m, 64);
            int   ok = __shfl_xor(bk, m, 64);
            if (os < bs || (os == bs && ok < bk)) { bs = os; bk = ok; }
        }
        if (lane == 0) indf[n] = (float)bk;
    }
}

// ---------------------------------------------------------------------------
// Kernel 4: gather outputs (overwrites the scratch regions last)
// ---------------------------------------------------------------------------
__global__ void vq_gather(const float* __restrict__ embed,
                          const float* __restrict__ indf,
                          float* __restrict__ out0,
                          float* __restrict__ out1) {
    int gid = blockIdx.x * 256 + threadIdx.x;        // BDHW/4 threads
    int w4   = (gid & 15) * 4;
    int rest = gid >> 4;
    int h  = rest & 63;
    int bd = rest >> 6;
    int d  = bd & 255;
    int b  = bd >> 8;
    int n  = (b * 64 + h) * 64 + w4;
    float4 fi = *reinterpret_cast<const float4*>(indf + n);
    const float* erow = embed + (size_t)d * K_CODES;
    float4 q;
    q.x = erow[(int)fi.x];
    q.y = erow[(int)fi.y];
    q.z = erow[(int)fi.z];
    q.w = erow[(int)fi.w];
    size_t o = (size_t)gid * 4;
    *reinterpret_cast<float4*>(out0 + o) = q;
    *reinterpret_cast<float4*>(out1 + o) = q;
}

// ---------------------------------------------------------------------------
extern "C" void kernel_launch(void* const* d_in, const int* in_sizes, int n_in,
                              void* d_out, int out_size, void* d_ws, size_t ws_size,
                              hipStream_t stream) {
    const float* input = (const float*)d_in[0];      // [32, 256, 64, 64] f32
    const float* embed = (const float*)d_in[1];      // [256, 1024] f32
    float* out0 = (float*)d_out;
    float* out1 = out0 + (size_t)BDHW;
    float* indf = out0 + (size_t)2 * BDHW;

    // scratch inside d_out (overwritten by vq_gather at the end):
    unsigned short* embT = (unsigned short*)out0;    // 512 KB bf16 [K][D]
    float* enorm = out0 + 131072;                    // 4 KB
    int* count = (int*)out1;
    int* list  = (int*)out1 + 1;

    vq_prep  <<<K_CODES / 256, 256, 0, stream>>>(embed, embT, enorm, count);
    vq_argmin<<<N_POS / 128,   256, 0, stream>>>(input, embT, enorm, indf, count, list);
    vq_refine<<<512,           256, 0, stream>>>(input, embed, enorm, indf, count, list);
    vq_gather<<<BDHW / 1024,   256, 0, stream>>>(embed, indf, out0, out1);
}

// Round 3
// 423.946 us; speedup vs baseline: 3.2427x; 3.1422x over previous
//
#include <hip/hip_runtime.h>

#define D_DIM 256
#define K_CODES 1024
#define HW 4096                  // H*W
#define BDHW 33554432            // 32*256*64*64
#define N_POS 131072             // 32*64*64
#define TAU 0.25f                // ~14 sigma of f16 pair-error (sigma ~ 0.018)

typedef __attribute__((ext_vector_type(8))) _Float16 half8v;
typedef __attribute__((ext_vector_type(4))) float float4v;

// ---------------------------------------------------------------------------
// Kernel 1: prep — embT[k][d] = f16(embed[d][k]); enorm[k] = sum_d e^2 (fp32)
// ---------------------------------------------------------------------------
__global__ void vq_prep(const float* __restrict__ embed,
                        _Float16* __restrict__ embT,
                        float* __restrict__ enorm,
                        int* __restrict__ count) {
    int k = blockIdx.x * 256 + threadIdx.x;          // 4 blocks
    float s = 0.f;
#pragma unroll 8
    for (int d = 0; d < D_DIM; ++d) {
        float e = embed[(size_t)d * K_CODES + k];
        s = fmaf(e, e, s);
        embT[(size_t)k * D_DIM + d] = (_Float16)e;
    }
    enorm[k] = s;
    if (k == 0) *count = 0;
}

// ---------------------------------------------------------------------------
// Kernel 2: f16 MFMA approximate distances + argmin with (min1,idx1,min2).
// Block: 256 thr (4 waves, 2x2), 128 positions x all 1024 codes.
// A (x f16) [128 pos][256 d] in LDS (64 KB, XOR-swizzled), staged once.
// B (embT)  [128 k][64 d] in LDS (16 KB), staged per (nc,dc).
// ---------------------------------------------------------------------------
__launch_bounds__(256, 2)
__global__ void vq_argmin(const float* __restrict__ input,
                          const _Float16* __restrict__ embT,
                          const float* __restrict__ enorm,
                          float* __restrict__ indf,
                          int* __restrict__ count,
                          int* __restrict__ list) {
    __shared__ __align__(16) char lds[81920];
    char* Als = lds;                 // 64 KB
    char* Bls = lds + 65536;         // 16 KB

    const int t   = threadIdx.x;
    const int blk = blockIdx.x;                      // 1024 blocks
    const int n0  = blk * 128;
    const int b   = n0 >> 12;
    const int h0  = (n0 & 4095) >> 6;                // rows h0, h0+1

    // ---- stage A: input[b, d, h0..h0+1, 0..63] -> f16 swizzled LDS
    const float* xbase = input + (size_t)b * (D_DIM * HW) + h0 * 64;
#pragma unroll 8
    for (int i = 0; i < 32; ++i) {
        int id = i * 256 + t;                        // 8192 float4
        int d  = id >> 5;
        int p4 = id & 31;
        int hoff = p4 >> 4;
        int w4   = (p4 & 15) << 2;
        float4 v = *reinterpret_cast<const float4*>(xbase + (size_t)d * HW + hoff * 64 + w4);
        int pos = hoff * 64 + w4;
        float vv[4] = {v.x, v.y, v.z, v.w};
#pragma unroll
        for (int j = 0; j < 4; ++j) {
            int r = pos + j;
            int byte = r * 512 + ((((d >> 3)) ^ (r & 7)) << 4) + ((d & 7) << 1);
            *reinterpret_cast<_Float16*>(Als + byte) = (_Float16)vv[j];
        }
    }
    __syncthreads();

    const int lane = t & 63;
    const int wid  = t >> 6;
    const int wm = wid >> 1, wn = wid & 1;           // wave tile: 64 pos x 64 codes
    const int l15 = lane & 15, l4 = lane >> 4;

    float m1[4][4], m2[4][4];
    int   i1[4][4];
#pragma unroll
    for (int mi = 0; mi < 4; ++mi)
#pragma unroll
        for (int r = 0; r < 4; ++r) { m1[mi][r] = 3.402823466e38f; m2[mi][r] = 3.402823466e38f; i1[mi][r] = 0; }

    for (int nc = 0; nc < 8; ++nc) {
        float4v acc[4][4];
#pragma unroll
        for (int mi = 0; mi < 4; ++mi)
#pragma unroll
            for (int ni = 0; ni < 4; ++ni) acc[mi][ni] = (float4v){0.f, 0.f, 0.f, 0.f};

        for (int dc = 0; dc < 4; ++dc) {
            __syncthreads();                         // previous B readers done
#pragma unroll
            for (int i = 0; i < 4; ++i) {            // stage B 16 KB
                int id = i * 256 + t;                // 1024 x 16B
                int r = id >> 3, slot = id & 7;
                uint4 v = *reinterpret_cast<const uint4*>(
                    embT + ((size_t)(nc * 128 + r)) * D_DIM + dc * 64 + slot * 8);
                *reinterpret_cast<uint4*>(Bls + r * 128 + ((slot ^ (r & 7)) << 4)) = v;
            }
            __syncthreads();

            half8v aF[4][2], bF[4][2];
#pragma unroll
            for (int mi = 0; mi < 4; ++mi)
#pragma unroll
                for (int ks = 0; ks < 2; ++ks) {
                    int r = wm * 64 + mi * 16 + l15;
                    int slot = dc * 8 + ks * 4 + l4;
                    aF[mi][ks] = *reinterpret_cast<const half8v*>(Als + r * 512 + ((slot ^ (r & 7)) << 4));
                }
#pragma unroll
            for (int ni = 0; ni < 4; ++ni)
#pragma unroll
                for (int ks = 0; ks < 2; ++ks) {
                    int r = wn * 64 + ni * 16 + l15;
                    int slot = ks * 4 + l4;
                    bF[ni][ks] = *reinterpret_cast<const half8v*>(Bls + r * 128 + ((slot ^ (r & 7)) << 4));
                }
#pragma unroll
            for (int mi = 0; mi < 4; ++mi)
#pragma unroll
                for (int ni = 0; ni < 4; ++ni) {
                    acc[mi][ni] = __builtin_amdgcn_mfma_f32_16x16x32_f16(aF[mi][0], bF[ni][0], acc[mi][ni], 0, 0, 0);
                    acc[mi][ni] = __builtin_amdgcn_mfma_f32_16x16x32_f16(aF[mi][1], bF[ni][1], acc[mi][ni], 0, 0, 0);
                }
        }

        // epilogue for this 128-code chunk: s = enorm - 2*dot, update (m1,i1,m2)
#pragma unroll
        for (int ni = 0; ni < 4; ++ni) {
            int code = nc * 128 + wn * 64 + ni * 16 + l15;
            float en = enorm[code];
#pragma unroll
            for (int mi = 0; mi < 4; ++mi)
#pragma unroll
                for (int r = 0; r < 4; ++r) {
                    float s = fmaf(-2.f, acc[mi][ni][r], en);
                    if (s < m1[mi][r]) { m2[mi][r] = m1[mi][r]; m1[mi][r] = s; i1[mi][r] = code; }
                    else m2[mi][r] = fminf(m2[mi][r], s);
                }
        }
    }

    // butterfly across the 16 column-lanes (lex-min on (val, idx), keep min2)
#pragma unroll
    for (int mi = 0; mi < 4; ++mi)
#pragma unroll
        for (int r = 0; r < 4; ++r) {
            float a1 = m1[mi][r], a2 = m2[mi][r]; int ai = i1[mi][r];
#pragma unroll
            for (int m = 8; m >= 1; m >>= 1) {
                float b1 = __shfl_xor(a1, m, 64);
                float b2 = __shfl_xor(a2, m, 64);
                int   bi = __shfl_xor(ai, m, 64);
                bool take = (b1 < a1) || (b1 == a1 && bi < ai);
                float hi = take ? a1 : b1;
                a1 = take ? b1 : a1;
                ai = take ? bi : ai;
                a2 = fminf(fminf(a2, b2), hi);
            }
            m1[mi][r] = a1; m2[mi][r] = a2; i1[mi][r] = ai;
        }

    __syncthreads();                                 // done reading A; reuse LDS
    float* Lm1 = reinterpret_cast<float*>(Als);      // [2][128]
    float* Lm2 = Lm1 + 256;
    int*   Li1 = reinterpret_cast<int*>(Lm2 + 256);
    if (l15 == 0) {
#pragma unroll
        for (int mi = 0; mi < 4; ++mi)
#pragma unroll
            for (int r = 0; r < 4; ++r) {
                int pos = wm * 64 + mi * 16 + l4 * 4 + r;
                Lm1[wn * 128 + pos] = m1[mi][r];
                Lm2[wn * 128 + pos] = m2[mi][r];
                Li1[wn * 128 + pos] = i1[mi][r];
            }
    }
    __syncthreads();
    if (t < 128) {
        float a1 = Lm1[t], a2 = Lm2[t]; int ai = Li1[t];
        float b1 = Lm1[128 + t], b2 = Lm2[128 + t]; int bi = Li1[128 + t];
        bool take = (b1 < a1) || (b1 == a1 && bi < ai);
        float hi = take ? a1 : b1;
        float f1 = take ? b1 : a1;
        int   fi = take ? bi : ai;
        float f2 = fminf(fminf(a2, b2), hi);
        int n = n0 + t;
        indf[n] = (float)fi;
        if (f2 - f1 < TAU) {                         // near-tie: exact rescan later
            int slot = atomicAdd(count, 1);
            list[slot] = n;
        }
    }
}

// ---------------------------------------------------------------------------
// Kernel 3: exact fp32 rescan for flagged positions (one wave per position).
// v2: 64 lanes cooperatively load x (4 strided loads each, 64 lines in flight)
// into LDS, then the K-scan reads x via LDS broadcast. Same fp32 summation
// order as the passing round-1/2 kernels.
// ---------------------------------------------------------------------------
__launch_bounds__(256, 4)
__global__ void vq_refine(const float* __restrict__ input,
                          const float* __restrict__ embed,
                          const float* __restrict__ enorm,
                          float* __restrict__ indf,
                          const int* __restrict__ count,
                          const int* __restrict__ list) {
    __shared__ float xls[4][D_DIM];
    const int wslot = threadIdx.x >> 6;
    const int lane  = threadIdx.x & 63;
    const int gw    = blockIdx.x * 4 + wslot;
    const int nw    = gridDim.x * 4;
    const int cnt   = *count;
    for (int i = gw; i < cnt; i += nw) {
        int n = list[i];
        int b = n >> 12, rem = n & 4095;             // rem = h*64 + w
        const float* xp = input + (size_t)b * (D_DIM * HW) + rem;
        float xv[4];
#pragma unroll
        for (int j = 0; j < 4; ++j) xv[j] = xp[(size_t)(j * 64 + lane) * HW];
#pragma unroll
        for (int j = 0; j < 4; ++j) xls[wslot][j * 64 + lane] = xv[j];
        asm volatile("s_waitcnt lgkmcnt(0)" ::: "memory");
        __builtin_amdgcn_sched_barrier(0);

        const float* ep = embed + lane * 16;
        float acc[16];
#pragma unroll
        for (int j = 0; j < 16; ++j) acc[j] = 0.f;
        for (int d = 0; d < D_DIM; ++d) {
            float xd = xls[wslot][d];
            const float* er = ep + (size_t)d * K_CODES;
            float4 e0 = *reinterpret_cast<const float4*>(er);
            float4 e1 = *reinterpret_cast<const float4*>(er + 4);
            float4 e2 = *reinterpret_cast<const float4*>(er + 8);
            float4 e3 = *reinterpret_cast<const float4*>(er + 12);
            float ea[16] = {e0.x, e0.y, e0.z, e0.w, e1.x, e1.y, e1.z, e1.w,
                            e2.x, e2.y, e2.z, e2.w, e3.x, e3.y, e3.z, e3.w};
#pragma unroll
            for (int j = 0; j < 16; ++j) acc[j] = fmaf(xd, ea[j], acc[j]);
        }
        float bs = 3.402823466e38f; int bk = 0;
#pragma unroll
        for (int j = 0; j < 16; ++j) {
            float s = fmaf(-2.f, acc[j], enorm[lane * 16 + j]);
            if (s < bs) { bs = s; bk = lane * 16 + j; }
        }
#pragma unroll
        for (int m = 32; m >= 1; m >>= 1) {
            float os = __shfl_xor(bs, m, 64);
            int   ok = __shfl_xor(bk, m, 64);
            if (os < bs || (os == bs && ok < bk)) { bs = os; bk = ok; }
        }
        if (lane == 0) indf[n] = (float)bk;
    }
}

// ---------------------------------------------------------------------------
// Kernel 4: gather outputs (overwrites the scratch regions last)
// ---------------------------------------------------------------------------
__global__ void vq_gather(const float* __restrict__ embed,
                          const float* __restrict__ indf,
                          float* __restrict__ out0,
                          float* __restrict__ out1) {
    int gid = blockIdx.x * 256 + threadIdx.x;        // BDHW/4 threads
    int w4   = (gid & 15) * 4;
    int rest = gid >> 4;
    int h  = rest & 63;
    int bd = rest >> 6;
    int d  = bd & 255;
    int b  = bd >> 8;
    int n  = (b * 64 + h) * 64 + w4;
    float4 fi = *reinterpret_cast<const float4*>(indf + n);
    const float* erow = embed + (size_t)d * K_CODES;
    float4 q;
    q.x = erow[(int)fi.x];
    q.y = erow[(int)fi.y];
    q.z = erow[(int)fi.z];
    q.w = erow[(int)fi.w];
    size_t o = (size_t)gid * 4;
    *reinterpret_cast<float4*>(out0 + o) = q;
    *reinterpret_cast<float4*>(out1 + o) = q;
}

// ---------------------------------------------------------------------------
extern "C" void kernel_launch(void* const* d_in, const int* in_sizes, int n_in,
                              void* d_out, int out_size, void* d_ws, size_t ws_size,
                              hipStream_t stream) {
    const float* input = (const float*)d_in[0];      // [32, 256, 64, 64] f32
    const float* embed = (const float*)d_in[1];      // [256, 1024] f32
    float* out0 = (float*)d_out;
    float* out1 = out0 + (size_t)BDHW;
    float* indf = out0 + (size_t)2 * BDHW;

    // scratch inside d_out (overwritten by vq_gather at the end):
    _Float16* embT = (_Float16*)out0;                // 512 KB f16 [K][D]
    float* enorm = out0 + 131072;                    // 4 KB
    int* count = (int*)out1;
    int* list  = (int*)out1 + 1;

    vq_prep  <<<K_CODES / 256, 256, 0, stream>>>(embed, embT, enorm, count);
    vq_argmin<<<N_POS / 128,   256, 0, stream>>>(input, embT, enorm, indf, count, list);
    vq_refine<<<512,           256, 0, stream>>>(input, embed, enorm, indf, count, list);
    vq_gather<<<BDHW / 1024,   256, 0, stream>>>(embed, indf, out0, out1);
}

// Round 4
// 284.844 us; speedup vs baseline: 4.8262x; 1.4883x over previous
//
#include <hip/hip_runtime.h>

#define D_DIM 256
#define K_CODES 1024
#define HW 4096                  // H*W
#define BDHW 33554432            // 32*256*64*64
#define N_POS 131072             // 32*64*64
#define TAU 0.25f                // ~14 sigma of f16 pair-error (sigma ~ 0.018)

typedef __attribute__((ext_vector_type(8))) _Float16 half8v;
typedef __attribute__((ext_vector_type(4))) float float4v;

// ---------------------------------------------------------------------------
// Kernel 1: prep — embT[k][d] = f16(embed[d][k]); enorm[k] = sum_d e^2 (fp32)
// ---------------------------------------------------------------------------
__global__ void vq_prep(const float* __restrict__ embed,
                        _Float16* __restrict__ embT,
                        float* __restrict__ enorm,
                        int* __restrict__ count) {
    int k = blockIdx.x * 256 + threadIdx.x;          // 4 blocks
    float s = 0.f;
#pragma unroll 8
    for (int d = 0; d < D_DIM; ++d) {
        float e = embed[(size_t)d * K_CODES + k];
        s = fmaf(e, e, s);
        embT[(size_t)k * D_DIM + d] = (_Float16)e;
    }
    enorm[k] = s;
    if (k == 0) *count = 0;
}

// ---------------------------------------------------------------------------
// Kernel 2: f16 MFMA approximate distances + argmin with (min1,idx1,min2).
// Block: 256 thr (4 waves, 2x2), 128 positions x all 1024 codes.
// A (x f16) [128 pos][256 d] in LDS (64 KB, XOR-swizzled), staged once.
// B (embT)  [128 k][64 d] in LDS (16 KB), staged per (nc,dc).
// ---------------------------------------------------------------------------
__launch_bounds__(256, 2)
__global__ void vq_argmin(const float* __restrict__ input,
                          const _Float16* __restrict__ embT,
                          const float* __restrict__ enorm,
                          float* __restrict__ indf,
                          int* __restrict__ count,
                          int* __restrict__ list) {
    __shared__ __align__(16) char lds[81920];
    char* Als = lds;                 // 64 KB
    char* Bls = lds + 65536;         // 16 KB

    const int t   = threadIdx.x;
    const int blk = blockIdx.x;                      // 1024 blocks
    const int n0  = blk * 128;
    const int b   = n0 >> 12;
    const int h0  = (n0 & 4095) >> 6;                // rows h0, h0+1

    // ---- stage A: input[b, d, h0..h0+1, 0..63] -> f16 swizzled LDS
    const float* xbase = input + (size_t)b * (D_DIM * HW) + h0 * 64;
#pragma unroll 8
    for (int i = 0; i < 32; ++i) {
        int id = i * 256 + t;                        // 8192 float4
        int d  = id >> 5;
        int p4 = id & 31;
        int hoff = p4 >> 4;
        int w4   = (p4 & 15) << 2;
        float4 v = *reinterpret_cast<const float4*>(xbase + (size_t)d * HW + hoff * 64 + w4);
        int pos = hoff * 64 + w4;
        float vv[4] = {v.x, v.y, v.z, v.w};
#pragma unroll
        for (int j = 0; j < 4; ++j) {
            int r = pos + j;
            int byte = r * 512 + ((((d >> 3)) ^ (r & 7)) << 4) + ((d & 7) << 1);
            *reinterpret_cast<_Float16*>(Als + byte) = (_Float16)vv[j];
        }
    }
    __syncthreads();

    const int lane = t & 63;
    const int wid  = t >> 6;
    const int wm = wid >> 1, wn = wid & 1;           // wave tile: 64 pos x 64 codes
    const int l15 = lane & 15, l4 = lane >> 4;

    float m1[4][4], m2[4][4];
    int   i1[4][4];
#pragma unroll
    for (int mi = 0; mi < 4; ++mi)
#pragma unroll
        for (int r = 0; r < 4; ++r) { m1[mi][r] = 3.402823466e38f; m2[mi][r] = 3.402823466e38f; i1[mi][r] = 0; }

    for (int nc = 0; nc < 8; ++nc) {
        float4v acc[4][4];
#pragma unroll
        for (int mi = 0; mi < 4; ++mi)
#pragma unroll
            for (int ni = 0; ni < 4; ++ni) acc[mi][ni] = (float4v){0.f, 0.f, 0.f, 0.f};

        for (int dc = 0; dc < 4; ++dc) {
            __syncthreads();                         // previous B readers done
#pragma unroll
            for (int i = 0; i < 4; ++i) {            // stage B 16 KB
                int id = i * 256 + t;                // 1024 x 16B
                int r = id >> 3, slot = id & 7;
                uint4 v = *reinterpret_cast<const uint4*>(
                    embT + ((size_t)(nc * 128 + r)) * D_DIM + dc * 64 + slot * 8);
                *reinterpret_cast<uint4*>(Bls + r * 128 + ((slot ^ (r & 7)) << 4)) = v;
            }
            __syncthreads();

            half8v aF[4][2], bF[4][2];
#pragma unroll
            for (int mi = 0; mi < 4; ++mi)
#pragma unroll
                for (int ks = 0; ks < 2; ++ks) {
                    int r = wm * 64 + mi * 16 + l15;
                    int slot = dc * 8 + ks * 4 + l4;
                    aF[mi][ks] = *reinterpret_cast<const half8v*>(Als + r * 512 + ((slot ^ (r & 7)) << 4));
                }
#pragma unroll
            for (int ni = 0; ni < 4; ++ni)
#pragma unroll
                for (int ks = 0; ks < 2; ++ks) {
                    int r = wn * 64 + ni * 16 + l15;
                    int slot = ks * 4 + l4;
                    bF[ni][ks] = *reinterpret_cast<const half8v*>(Bls + r * 128 + ((slot ^ (r & 7)) << 4));
                }
#pragma unroll
            for (int mi = 0; mi < 4; ++mi)
#pragma unroll
                for (int ni = 0; ni < 4; ++ni) {
                    acc[mi][ni] = __builtin_amdgcn_mfma_f32_16x16x32_f16(aF[mi][0], bF[ni][0], acc[mi][ni], 0, 0, 0);
                    acc[mi][ni] = __builtin_amdgcn_mfma_f32_16x16x32_f16(aF[mi][1], bF[ni][1], acc[mi][ni], 0, 0, 0);
                }
        }

        // epilogue for this 128-code chunk: s = enorm - 2*dot, update (m1,i1,m2)
#pragma unroll
        for (int ni = 0; ni < 4; ++ni) {
            int code = nc * 128 + wn * 64 + ni * 16 + l15;
            float en = enorm[code];
#pragma unroll
            for (int mi = 0; mi < 4; ++mi)
#pragma unroll
                for (int r = 0; r < 4; ++r) {
                    float s = fmaf(-2.f, acc[mi][ni][r], en);
                    if (s < m1[mi][r]) { m2[mi][r] = m1[mi][r]; m1[mi][r] = s; i1[mi][r] = code; }
                    else m2[mi][r] = fminf(m2[mi][r], s);
                }
        }
    }

    // butterfly across the 16 column-lanes (lex-min on (val, idx), keep min2)
#pragma unroll
    for (int mi = 0; mi < 4; ++mi)
#pragma unroll
        for (int r = 0; r < 4; ++r) {
            float a1 = m1[mi][r], a2 = m2[mi][r]; int ai = i1[mi][r];
#pragma unroll
            for (int m = 8; m >= 1; m >>= 1) {
                float b1 = __shfl_xor(a1, m, 64);
                float b2 = __shfl_xor(a2, m, 64);
                int   bi = __shfl_xor(ai, m, 64);
                bool take = (b1 < a1) || (b1 == a1 && bi < ai);
                float hi = take ? a1 : b1;
                a1 = take ? b1 : a1;
                ai = take ? bi : ai;
                a2 = fminf(fminf(a2, b2), hi);
            }
            m1[mi][r] = a1; m2[mi][r] = a2; i1[mi][r] = ai;
        }

    __syncthreads();                                 // done reading A; reuse LDS
    float* Lm1 = reinterpret_cast<float*>(Als);      // [2][128]
    float* Lm2 = Lm1 + 256;
    int*   Li1 = reinterpret_cast<int*>(Lm2 + 256);
    if (l15 == 0) {
#pragma unroll
        for (int mi = 0; mi < 4; ++mi)
#pragma unroll
            for (int r = 0; r < 4; ++r) {
                int pos = wm * 64 + mi * 16 + l4 * 4 + r;
                Lm1[wn * 128 + pos] = m1[mi][r];
                Lm2[wn * 128 + pos] = m2[mi][r];
                Li1[wn * 128 + pos] = i1[mi][r];
            }
    }
    __syncthreads();
    if (t < 128) {
        float a1 = Lm1[t], a2 = Lm2[t]; int ai = Li1[t];
        float b1 = Lm1[128 + t], b2 = Lm2[128 + t]; int bi = Li1[128 + t];
        bool take = (b1 < a1) || (b1 == a1 && bi < ai);
        float hi = take ? a1 : b1;
        float f1 = take ? b1 : a1;
        int   fi = take ? bi : ai;
        float f2 = fminf(fminf(a2, b2), hi);
        int n = n0 + t;
        indf[n] = (float)fi;
        if (f2 - f1 < TAU) {                         // near-tie: exact rescan later
            int slot = atomicAdd(count, 1);
            list[slot] = n;
        }
    }
}

// ---------------------------------------------------------------------------
// Kernel 3: exact fp32 rescan, v3 — 4 flagged positions per wave.
// The wave stages 4 x-vectors into LDS (cooperative strided loads), then one
// shared K-scan: per d, load 16 embed floats/lane once and FMA into 4 position
// accumulators (64 FMA/lane between load batches -> latency hidden, 4x less
// L2 traffic). fp32 order and tie-break identical to the passing version.
// ---------------------------------------------------------------------------
__launch_bounds__(256, 2)
__global__ void vq_refine(const float* __restrict__ input,
                          const float* __restrict__ embed,
                          const float* __restrict__ enorm,
                          float* __restrict__ indf,
                          const int* __restrict__ count,
                          const int* __restrict__ list) {
    __shared__ float xls[4][4][D_DIM];
    const int wslot = threadIdx.x >> 6;
    const int lane  = threadIdx.x & 63;
    const int gw    = blockIdx.x * 4 + wslot;
    const int nw    = gridDim.x * 4;
    const int cnt   = *count;
    if (cnt == 0) return;
    const int ngroups = (cnt + 3) >> 2;

    const float* ep = embed + lane * 16;
    float en[16];
    {
        float4 e0 = *reinterpret_cast<const float4*>(enorm + lane * 16);
        float4 e1 = *reinterpret_cast<const float4*>(enorm + lane * 16 + 4);
        float4 e2 = *reinterpret_cast<const float4*>(enorm + lane * 16 + 8);
        float4 e3 = *reinterpret_cast<const float4*>(enorm + lane * 16 + 12);
        en[0]=e0.x; en[1]=e0.y; en[2]=e0.z; en[3]=e0.w;
        en[4]=e1.x; en[5]=e1.y; en[6]=e1.z; en[7]=e1.w;
        en[8]=e2.x; en[9]=e2.y; en[10]=e2.z; en[11]=e2.w;
        en[12]=e3.x; en[13]=e3.y; en[14]=e3.z; en[15]=e3.w;
    }

    for (int g = gw; g < ngroups; g += nw) {
        int np[4];
        const float* bp[4];
#pragma unroll
        for (int p = 0; p < 4; ++p) {
            int li = g * 4 + p; if (li >= cnt) li = cnt - 1;   // tail dup: benign
            np[p] = list[li];
            int b = np[p] >> 12, rem = np[p] & 4095;           // rem = h*64+w
            bp[p] = input + (size_t)b * (D_DIM * HW) + rem;
        }
        // cooperative load: 16 independent strided lines per lane
#pragma unroll
        for (int j = 0; j < 16; ++j) {
            int p = j >> 2;
            int d = (j & 3) * 64 + lane;
            xls[wslot][p][d] = bp[p][(size_t)d * HW];
        }
        asm volatile("s_waitcnt lgkmcnt(0)" ::: "memory");
        __builtin_amdgcn_sched_barrier(0);

        float acc[4][16];
#pragma unroll
        for (int p = 0; p < 4; ++p)
#pragma unroll
            for (int j = 0; j < 16; ++j) acc[p][j] = 0.f;

#pragma unroll 2
        for (int d = 0; d < D_DIM; ++d) {
            const float* er = ep + (size_t)d * K_CODES;
            float4 e0 = *reinterpret_cast<const float4*>(er);
            float4 e1 = *reinterpret_cast<const float4*>(er + 4);
            float4 e2 = *reinterpret_cast<const float4*>(er + 8);
            float4 e3 = *reinterpret_cast<const float4*>(er + 12);
            float ea[16] = {e0.x, e0.y, e0.z, e0.w, e1.x, e1.y, e1.z, e1.w,
                            e2.x, e2.y, e2.z, e2.w, e3.x, e3.y, e3.z, e3.w};
            float xd[4] = {xls[wslot][0][d], xls[wslot][1][d],
                           xls[wslot][2][d], xls[wslot][3][d]};
#pragma unroll
            for (int p = 0; p < 4; ++p)
#pragma unroll
                for (int j = 0; j < 16; ++j)
                    acc[p][j] = fmaf(xd[p], ea[j], acc[p][j]);
        }

#pragma unroll
        for (int p = 0; p < 4; ++p) {
            float bs = 3.402823466e38f; int bk = 0;
#pragma unroll
            for (int j = 0; j < 16; ++j) {
                float s = fmaf(-2.f, acc[p][j], en[j]);
                if (s < bs) { bs = s; bk = lane * 16 + j; }
            }
#pragma unroll
            for (int m = 32; m >= 1; m >>= 1) {
                float os = __shfl_xor(bs, m, 64);
                int   ok = __shfl_xor(bk, m, 64);
                if (os < bs || (os == bs && ok < bk)) { bs = os; bk = ok; }
            }
            if (lane == 0) indf[np[p]] = (float)bk;
        }
        __syncthreads();   // keep waves of the block loosely together for LDS reuse
    }
}

// ---------------------------------------------------------------------------
// Kernel 4: gather outputs (overwrites the scratch regions last)
// ---------------------------------------------------------------------------
__global__ void vq_gather(const float* __restrict__ embed,
                          const float* __restrict__ indf,
                          float* __restrict__ out0,
                          float* __restrict__ out1) {
    int gid = blockIdx.x * 256 + threadIdx.x;        // BDHW/4 threads
    int w4   = (gid & 15) * 4;
    int rest = gid >> 4;
    int h  = rest & 63;
    int bd = rest >> 6;
    int d  = bd & 255;
    int b  = bd >> 8;
    int n  = (b * 64 + h) * 64 + w4;
    float4 fi = *reinterpret_cast<const float4*>(indf + n);
    const float* erow = embed + (size_t)d * K_CODES;
    float4 q;
    q.x = erow[(int)fi.x];
    q.y = erow[(int)fi.y];
    q.z = erow[(int)fi.z];
    q.w = erow[(int)fi.w];
    size_t o = (size_t)gid * 4;
    *reinterpret_cast<float4*>(out0 + o) = q;
    *reinterpret_cast<float4*>(out1 + o) = q;
}

// ---------------------------------------------------------------------------
extern "C" void kernel_launch(void* const* d_in, const int* in_sizes, int n_in,
                              void* d_out, int out_size, void* d_ws, size_t ws_size,
                              hipStream_t stream) {
    const float* input = (const float*)d_in[0];      // [32, 256, 64, 64] f32
    const float* embed = (const float*)d_in[1];      // [256, 1024] f32
    float* out0 = (float*)d_out;
    float* out1 = out0 + (size_t)BDHW;
    float* indf = out0 + (size_t)2 * BDHW;

    // scratch inside d_out (overwritten by vq_gather at the end):
    _Float16* embT = (_Float16*)out0;                // 512 KB f16 [K][D]
    float* enorm = out0 + 131072;                    // 4 KB
    int* count = (int*)out1;
    int* list  = (int*)out1 + 1;

    vq_prep  <<<K_CODES / 256, 256, 0, stream>>>(embed, embT, enorm, count);
    vq_argmin<<<N_POS / 128,   256, 0, stream>>>(input, embT, enorm, indf, count, list);
    vq_refine<<<256,           256, 0, stream>>>(input, embed, enorm, indf, count, list);
    vq_gather<<<BDHW / 1024,   256, 0, stream>>>(embed, indf, out0, out1);
}

// Round 5
// 263.392 us; speedup vs baseline: 5.2193x; 1.0814x over previous
//
#include <hip/hip_runtime.h>

#define D_DIM 256
#define K_CODES 1024
#define HW 4096                  // H*W
#define BDHW 33554432            // 32*256*64*64
#define N_POS 131072             // 32*64*64
#define TAU 0.25f                // ~14 sigma of f16 pair-error

typedef __attribute__((ext_vector_type(8))) _Float16 half8v;
typedef __attribute__((ext_vector_type(4))) float float4v;

__device__ __forceinline__ void load_lds16(const void* g, void* l) {
    __builtin_amdgcn_global_load_lds(
        (const __attribute__((address_space(1))) unsigned int*)g,
        (__attribute__((address_space(3))) unsigned int*)l, 16, 0, 0);
}

// ---------------------------------------------------------------------------
// Kernel 1a: build pre-swizzled f16 embT: 64 chunks (nc,dc) of 8 KB whose
// LINEAR image equals the B-LDS layout: byte(r,sp) = r*64 + sp*16 holds
// embed[dc*32 + (sp ^ ((r>>1)&3))*8 + j][nc*128 + r], j=0..7.
// ---------------------------------------------------------------------------
__global__ void vq_prep(const float* __restrict__ embed, uint4* __restrict__ embT) {
    const int c  = blockIdx.x;                   // 64 chunks
    const int nc = c >> 3, dc = c & 7;
    const int t  = threadIdx.x;
#pragma unroll
    for (int i = 0; i < 2; ++i) {
        int p  = i * 256 + t;                    // piece 0..511 (16B each)
        int r  = p >> 2, sp = p & 3;
        int s  = sp ^ ((r >> 1) & 3);
        int k  = nc * 128 + r;
        int db = dc * 32 + s * 8;
        union { _Float16 h[8]; uint4 u; } pk;
#pragma unroll
        for (int j = 0; j < 8; ++j)
            pk.h[j] = (_Float16)embed[(size_t)(db + j) * K_CODES + k];
        embT[c * 512 + p] = pk.u;
    }
}

// ---------------------------------------------------------------------------
// Kernel 1b: enorm[k] = sum_d embed[d][k]^2 (fp32); zero refine counter.
// ---------------------------------------------------------------------------
__global__ void vq_enorm(const float* __restrict__ embed,
                         float* __restrict__ enorm, int* __restrict__ count) {
    __shared__ float part[256];
    const int t = threadIdx.x;
    const int k = blockIdx.x * 128 + (t & 127);
    const int hf = t >> 7;
    float s = 0.f;
#pragma unroll 4
    for (int d = hf * 128; d < hf * 128 + 128; ++d) {
        float e = embed[(size_t)d * K_CODES + k];
        s = fmaf(e, e, s);
    }
    part[t] = s;
    __syncthreads();
    if (t < 128) enorm[k] = part[t] + part[t + 128];
    if (blockIdx.x == 0 && t == 0) *count = 0;
}

// ---------------------------------------------------------------------------
// Kernel 2: f16 MFMA distances + argmin with (min1,idx1,min2).
// Block: 256 thr (4 waves 2x2), 128 pos x 1024 codes.
// A LDS 64 KB swizzled (staged once, b128 writes); B 2x8 KB double-buffered
// via global_load_lds from pre-swizzled embT; 2-phase pipeline, 1 barrier/step.
// ---------------------------------------------------------------------------
__launch_bounds__(256, 2)
__global__ void vq_argmin(const float* __restrict__ input,
                          const char* __restrict__ embT,
                          const float* __restrict__ enorm,
                          float* __restrict__ indf,
                          int* __restrict__ count,
                          int* __restrict__ list) {
    __shared__ __align__(16) char lds[81920];
    char* Als = lds;                             // 64 KB: byte(r,slot)=r*512+(((slot&24)|((slot&7)^(r&7)))<<4)
    char* Bls = lds + 65536;                     // 2 x 8 KB: byte(r,sp)=r*64+sp*16 (pre-swizzled content)

    const int t    = threadIdx.x;
    const int lane = t & 63;
    const int wid  = t >> 6;
    const int blk  = blockIdx.x;                 // 1024 blocks
    const int n0   = blk * 128;
    const int b    = n0 >> 12;
    const int h0   = (n0 & 4095) >> 6;           // rows h0, h0+1

    // ---- prologue: start B chunk 0 while staging A
    {
        const char* src = embT + (size_t)wid * 2048 + lane * 16;
        char* dst = Bls + wid * 2048;
        load_lds16(src, dst);
        load_lds16(src + 1024, dst + 1024);
    }

    // ---- stage A: coalesced dword loads + reg pack + swizzled b128 writes
    {
        const float* xbase = input + (size_t)b * (D_DIM * HW) + h0 * 64;
        const int g = wid;                       // slot group 0..3
#pragma unroll
        for (int half = 0; half < 2; ++half) {
            const int r = half * 64 + lane;
            const float* hp = xbase + half * 64 + lane;
            const int rowbyte = r * 512;
            const int r7 = r & 7;
#pragma unroll
            for (int q = 0; q < 8; ++q) {
                const int slot = g * 8 + q;
                const int db = slot * 8;
                float v[8];
#pragma unroll
                for (int j = 0; j < 8; ++j) v[j] = hp[(size_t)(db + j) * HW];
                union { _Float16 h[8]; uint4 u; } pk;
#pragma unroll
                for (int j = 0; j < 8; ++j) pk.h[j] = (_Float16)v[j];
                const int byte = rowbyte + (((slot & 24) | ((slot & 7) ^ r7)) << 4);
                *reinterpret_cast<uint4*>(Als + byte) = pk.u;
            }
        }
    }
    __syncthreads();                             // drains vmcnt+lgkmcnt: A and B0 ready

    const int wm = wid >> 1, wn = wid & 1;       // wave tile: 64 pos x 64 codes
    const int l15 = lane & 15, l4 = lane >> 4;

    // precomputed fragment addresses
    int aRow[4], aR7[4], bOfs[4];
#pragma unroll
    for (int mi = 0; mi < 4; ++mi) {
        int r = wm * 64 + mi * 16 + l15;
        aRow[mi] = r * 512;
        aR7[mi] = r & 7;
    }
#pragma unroll
    for (int ni = 0; ni < 4; ++ni) {
        int r = wn * 64 + ni * 16 + l15;
        bOfs[ni] = r * 64 + ((l4 ^ ((r >> 1) & 3)) << 4);
    }

    float m1[4][4], m2[4][4];
    int   i1[4][4];
#pragma unroll
    for (int mi = 0; mi < 4; ++mi)
#pragma unroll
        for (int r = 0; r < 4; ++r) { m1[mi][r] = 3.402823466e38f; m2[mi][r] = 3.402823466e38f; i1[mi][r] = 0; }

    for (int nc = 0; nc < 8; ++nc) {
        float4v acc[4][4];
#pragma unroll
        for (int mi = 0; mi < 4; ++mi)
#pragma unroll
            for (int ni = 0; ni < 4; ++ni) acc[mi][ni] = (float4v){0.f, 0.f, 0.f, 0.f};

#pragma unroll
        for (int dc = 0; dc < 8; ++dc) {
            const int step = nc * 8 + dc;
            char* curB = Bls + ((dc & 1) << 13);
            // stage next chunk into the other buffer (2-phase pipeline)
            if (step < 63) {
                const char* src = embT + (size_t)(step + 1) * 8192 + wid * 2048 + lane * 16;
                char* dst = Bls + (((dc & 1) ^ 1) << 13) + wid * 2048;
                load_lds16(src, dst);
                load_lds16(src + 1024, dst + 1024);
            }
            // fragment reads (conflict-free swizzles)
            half8v aF[4], bF[4];
            const int slot = dc * 4 + l4;
#pragma unroll
            for (int mi = 0; mi < 4; ++mi)
                aF[mi] = *reinterpret_cast<const half8v*>(
                    Als + aRow[mi] + (((slot & 24) | ((slot & 7) ^ aR7[mi])) << 4));
#pragma unroll
            for (int ni = 0; ni < 4; ++ni)
                bF[ni] = *reinterpret_cast<const half8v*>(curB + bOfs[ni]);
#pragma unroll
            for (int mi = 0; mi < 4; ++mi)
#pragma unroll
                for (int ni = 0; ni < 4; ++ni)
                    acc[mi][ni] = __builtin_amdgcn_mfma_f32_16x16x32_f16(aF[mi], bF[ni], acc[mi][ni], 0, 0, 0);
            __syncthreads();                     // drains vmcnt(0): next buffer landed
        }

        // epilogue for this 128-code chunk (registers + cached enorm only)
#pragma unroll
        for (int ni = 0; ni < 4; ++ni) {
            int code = nc * 128 + wn * 64 + ni * 16 + l15;
            float en = enorm[code];
#pragma unroll
            for (int mi = 0; mi < 4; ++mi)
#pragma unroll
                for (int r = 0; r < 4; ++r) {
                    float s = fmaf(-2.f, acc[mi][ni][r], en);
                    if (s < m1[mi][r]) { m2[mi][r] = m1[mi][r]; m1[mi][r] = s; i1[mi][r] = code; }
                    else m2[mi][r] = fminf(m2[mi][r], s);
                }
        }
    }

    // butterfly across the 16 column-lanes (lex-min on (val, idx), keep min2)
#pragma unroll
    for (int mi = 0; mi < 4; ++mi)
#pragma unroll
        for (int r = 0; r < 4; ++r) {
            float a1 = m1[mi][r], a2 = m2[mi][r]; int ai = i1[mi][r];
#pragma unroll
            for (int m = 8; m >= 1; m >>= 1) {
                float b1 = __shfl_xor(a1, m, 64);
                float b2 = __shfl_xor(a2, m, 64);
                int   bi = __shfl_xor(ai, m, 64);
                bool take = (b1 < a1) || (b1 == a1 && bi < ai);
                float hi = take ? a1 : b1;
                a1 = take ? b1 : a1;
                ai = take ? bi : ai;
                a2 = fminf(fminf(a2, b2), hi);
            }
            m1[mi][r] = a1; m2[mi][r] = a2; i1[mi][r] = ai;
        }

    __syncthreads();                             // done with A/B; reuse LDS
    float* Lm1 = reinterpret_cast<float*>(Als);  // [2][128]
    float* Lm2 = Lm1 + 256;
    int*   Li1 = reinterpret_cast<int*>(Lm2 + 256);
    if (l15 == 0) {
#pragma unroll
        for (int mi = 0; mi < 4; ++mi)
#pragma unroll
            for (int r = 0; r < 4; ++r) {
                int pos = wm * 64 + mi * 16 + l4 * 4 + r;
                Lm1[wn * 128 + pos] = m1[mi][r];
                Lm2[wn * 128 + pos] = m2[mi][r];
                Li1[wn * 128 + pos] = i1[mi][r];
            }
    }
    __syncthreads();
    if (t < 128) {
        float a1 = Lm1[t], a2 = Lm2[t]; int ai = Li1[t];
        float b1 = Lm1[128 + t], b2 = Lm2[128 + t]; int bi = Li1[128 + t];
        bool take = (b1 < a1) || (b1 == a1 && bi < ai);
        float hi = take ? a1 : b1;
        float f1 = take ? b1 : a1;
        int   fi = take ? bi : ai;
        float f2 = fminf(fminf(a2, b2), hi);
        int n = n0 + t;
        indf[n] = (float)fi;
        if (f2 - f1 < TAU) {                     // near-tie: exact rescan later
            int slot = atomicAdd(count, 1);
            list[slot] = n;
        }
    }
}

// ---------------------------------------------------------------------------
// Kernel 3: exact fp32 rescan — 4 flagged positions per wave (unchanged).
// ---------------------------------------------------------------------------
__launch_bounds__(256, 2)
__global__ void vq_refine(const float* __restrict__ input,
                          const float* __restrict__ embed,
                          const float* __restrict__ enorm,
                          float* __restrict__ indf,
                          const int* __restrict__ count,
                          const int* __restrict__ list) {
    __shared__ float xls[4][4][D_DIM];
    const int wslot = threadIdx.x >> 6;
    const int lane  = threadIdx.x & 63;
    const int gw    = blockIdx.x * 4 + wslot;
    const int nw    = gridDim.x * 4;
    const int cnt   = *count;
    if (cnt == 0) return;
    const int ngroups = (cnt + 3) >> 2;

    const float* ep = embed + lane * 16;
    float en[16];
    {
        float4 e0 = *reinterpret_cast<const float4*>(enorm + lane * 16);
        float4 e1 = *reinterpret_cast<const float4*>(enorm + lane * 16 + 4);
        float4 e2 = *reinterpret_cast<const float4*>(enorm + lane * 16 + 8);
        float4 e3 = *reinterpret_cast<const float4*>(enorm + lane * 16 + 12);
        en[0]=e0.x; en[1]=e0.y; en[2]=e0.z; en[3]=e0.w;
        en[4]=e1.x; en[5]=e1.y; en[6]=e1.z; en[7]=e1.w;
        en[8]=e2.x; en[9]=e2.y; en[10]=e2.z; en[11]=e2.w;
        en[12]=e3.x; en[13]=e3.y; en[14]=e3.z; en[15]=e3.w;
    }

    for (int g = gw; g < ngroups; g += nw) {
        int np[4];
        const float* bp[4];
#pragma unroll
        for (int p = 0; p < 4; ++p) {
            int li = g * 4 + p; if (li >= cnt) li = cnt - 1;   // tail dup: benign
            np[p] = list[li];
            int b = np[p] >> 12, rem = np[p] & 4095;
            bp[p] = input + (size_t)b * (D_DIM * HW) + rem;
        }
#pragma unroll
        for (int j = 0; j < 16; ++j) {
            int p = j >> 2;
            int d = (j & 3) * 64 + lane;
            xls[wslot][p][d] = bp[p][(size_t)d * HW];
        }
        asm volatile("s_waitcnt lgkmcnt(0)" ::: "memory");
        __builtin_amdgcn_sched_barrier(0);

        float acc[4][16];
#pragma unroll
        for (int p = 0; p < 4; ++p)
#pragma unroll
            for (int j = 0; j < 16; ++j) acc[p][j] = 0.f;

#pragma unroll 2
        for (int d = 0; d < D_DIM; ++d) {
            const float* er = ep + (size_t)d * K_CODES;
            float4 e0 = *reinterpret_cast<const float4*>(er);
            float4 e1 = *reinterpret_cast<const float4*>(er + 4);
            float4 e2 = *reinterpret_cast<const float4*>(er + 8);
            float4 e3 = *reinterpret_cast<const float4*>(er + 12);
            float ea[16] = {e0.x, e0.y, e0.z, e0.w, e1.x, e1.y, e1.z, e1.w,
                            e2.x, e2.y, e2.z, e2.w, e3.x, e3.y, e3.z, e3.w};
            float xd[4] = {xls[wslot][0][d], xls[wslot][1][d],
                           xls[wslot][2][d], xls[wslot][3][d]};
#pragma unroll
            for (int p = 0; p < 4; ++p)
#pragma unroll
                for (int j = 0; j < 16; ++j)
                    acc[p][j] = fmaf(xd[p], ea[j], acc[p][j]);
        }

#pragma unroll
        for (int p = 0; p < 4; ++p) {
            float bs = 3.402823466e38f; int bk = 0;
#pragma unroll
            for (int j = 0; j < 16; ++j) {
                float s = fmaf(-2.f, acc[p][j], en[j]);
                if (s < bs) { bs = s; bk = lane * 16 + j; }
            }
#pragma unroll
            for (int m = 32; m >= 1; m >>= 1) {
                float os = __shfl_xor(bs, m, 64);
                int   ok = __shfl_xor(bk, m, 64);
                if (os < bs || (os == bs && ok < bk)) { bs = os; bk = ok; }
            }
            if (lane == 0) indf[np[p]] = (float)bk;
        }
        __syncthreads();
    }
}

// ---------------------------------------------------------------------------
// Kernel 4: gather outputs (overwrites the scratch regions last)
// ---------------------------------------------------------------------------
__global__ void vq_gather(const float* __restrict__ embed,
                          const float* __restrict__ indf,
                          float* __restrict__ out0,
                          float* __restrict__ out1) {
    int gid = blockIdx.x * 256 + threadIdx.x;    // BDHW/4 threads
    int w4   = (gid & 15) * 4;
    int rest = gid >> 4;
    int h  = rest & 63;
    int bd = rest >> 6;
    int d  = bd & 255;
    int b  = bd >> 8;
    int n  = (b * 64 + h) * 64 + w4;
    float4 fi = *reinterpret_cast<const float4*>(indf + n);
    const float* erow = embed + (size_t)d * K_CODES;
    float4 q;
    q.x = erow[(int)fi.x];
    q.y = erow[(int)fi.y];
    q.z = erow[(int)fi.z];
    q.w = erow[(int)fi.w];
    size_t o = (size_t)gid * 4;
    *reinterpret_cast<float4*>(out0 + o) = q;
    *reinterpret_cast<float4*>(out1 + o) = q;
}

// ---------------------------------------------------------------------------
extern "C" void kernel_launch(void* const* d_in, const int* in_sizes, int n_in,
                              void* d_out, int out_size, void* d_ws, size_t ws_size,
                              hipStream_t stream) {
    const float* input = (const float*)d_in[0];  // [32, 256, 64, 64] f32
    const float* embed = (const float*)d_in[1];  // [256, 1024] f32
    float* out0 = (float*)d_out;
    float* out1 = out0 + (size_t)BDHW;
    float* indf = out0 + (size_t)2 * BDHW;

    // scratch inside d_out (overwritten by vq_gather at the end):
    uint4* embT  = (uint4*)out0;                 // 512 KB pre-swizzled f16 chunks
    float* enorm = out0 + 131072;                // 4 KB (right after embT)
    int* count = (int*)out1;
    int* list  = (int*)out1 + 1;

    vq_prep  <<<64,          256, 0, stream>>>(embed, embT);
    vq_enorm <<<8,           256, 0, stream>>>(embed, enorm, count);
    vq_argmin<<<N_POS / 128, 256, 0, stream>>>(input, (const char*)embT, enorm, indf, count, list);
    vq_refine<<<256,         256, 0, stream>>>(input, embed, enorm, indf, count, list);
    vq_gather<<<BDHW / 1024, 256, 0, stream>>>(embed, indf, out0, out1);
}

// Round 6
// 251.150 us; speedup vs baseline: 5.4737x; 1.0487x over previous
//
#include <hip/hip_runtime.h>

#define D_DIM 256
#define K_CODES 1024
#define HW 4096                  // H*W
#define BDHW 33554432            // 32*256*64*64
#define N_POS 131072             // 32*64*64
#define TAU 0.25f                // ~14 sigma of f16 pair-error

typedef __attribute__((ext_vector_type(8))) _Float16 half8v;
typedef __attribute__((ext_vector_type(4))) float float4v;

__device__ __forceinline__ void load_lds16(const void* g, void* l) {
    __builtin_amdgcn_global_load_lds(
        (const __attribute__((address_space(1))) unsigned int*)g,
        (__attribute__((address_space(3))) unsigned int*)l, 16, 0, 0);
}

// ---------------------------------------------------------------------------
// Kernel 1a: pre-swizzled f16 embT: 64 chunks (nc,dc) of 8 KB whose LINEAR
// image equals the B-LDS layout: byte(r,sp) = r*64 + sp*16 holds
// embed[dc*32 + (sp ^ ((r>>1)&3))*8 + j][nc*128 + r], j=0..7.
// ---------------------------------------------------------------------------
__global__ void vq_prep(const float* __restrict__ embed, uint4* __restrict__ embT) {
    const int c  = blockIdx.x;                   // 64 chunks
    const int nc = c >> 3, dc = c & 7;
    const int t  = threadIdx.x;
#pragma unroll
    for (int i = 0; i < 2; ++i) {
        int p  = i * 256 + t;                    // piece 0..511 (16B each)
        int r  = p >> 2, sp = p & 3;
        int s  = sp ^ ((r >> 1) & 3);
        int k  = nc * 128 + r;
        int db = dc * 32 + s * 8;
        union { _Float16 h[8]; uint4 u; } pk;
#pragma unroll
        for (int j = 0; j < 8; ++j)
            pk.h[j] = (_Float16)embed[(size_t)(db + j) * K_CODES + k];
        embT[c * 512 + p] = pk.u;
    }
}

// ---------------------------------------------------------------------------
// Kernel 1b: enorm[k] = sum_d embed[d][k]^2 (fp32); zero refine counter.
// ---------------------------------------------------------------------------
__global__ void vq_enorm(const float* __restrict__ embed,
                         float* __restrict__ enorm, int* __restrict__ count) {
    __shared__ float part[256];
    const int t = threadIdx.x;
    const int k = blockIdx.x * 128 + (t & 127);
    const int hf = t >> 7;
    float s = 0.f;
#pragma unroll 4
    for (int d = hf * 128; d < hf * 128 + 128; ++d) {
        float e = embed[(size_t)d * K_CODES + k];
        s = fmaf(e, e, s);
    }
    part[t] = s;
    __syncthreads();
    if (t < 128) enorm[k] = part[t] + part[t + 128];
    if (blockIdx.x == 0 && t == 0) *count = 0;
}

// ---------------------------------------------------------------------------
// Kernel 2: f16 MFMA distances + argmin with (min1,idx1,min2).
// 256 thr (4 waves 2Mx2N, wave tile 64 pos x 64 codes), 128 pos x 1024 codes.
// A d<128 in REGISTERS (16 half8v/wave); A d>=128 in 32 KB swizzled LDS.
// B: 4 x 8 KB LDS ring via global_load_lds from pre-swizzled embT,
// stage-ahead-2, counted vmcnt(4), ONE s_barrier per step (T3+T4).
// enorm cached in LDS so loop vmem = B stages only.
// ---------------------------------------------------------------------------
__launch_bounds__(256, 2)
__global__ void vq_argmin(const float* __restrict__ input,
                          const char* __restrict__ embT,
                          const float* __restrict__ enorm,
                          float* __restrict__ indf,
                          int* __restrict__ count,
                          int* __restrict__ list) {
    __shared__ __align__(16) char lds[69632];
    char*  Als = lds;                            // 32 KB: [r<128][slot<16] swizzled, d=128+slot*8+j
    char*  Bls = lds + 32768;                    // 4 x 8 KB B ring
    float* Els = (float*)(lds + 65536);          // 4 KB enorm

    const int t    = threadIdx.x;
    const int lane = t & 63;
    const int wid  = t >> 6;
    const int blk  = blockIdx.x;                 // 1024 blocks
    const int n0   = blk * 128;
    const int b    = n0 >> 12;
    const int h0   = (n0 & 4095) >> 6;           // rows h0, h0+1
    const int wm = wid >> 1, wn = wid & 1;
    const int l15 = lane & 15, l4 = lane >> 4;

    // ---- prologue: issue B stages 0,1 (2 x 1KB per wave each)
#pragma unroll
    for (int st = 0; st < 2; ++st) {
        const char* src = embT + (size_t)st * 8192 + wid * 2048 + lane * 16;
        char* dst = Bls + st * 8192 + wid * 2048;
        load_lds16(src, dst);
        load_lds16(src + 1024, dst + 1024);
    }

    // ---- stage enorm to LDS
    *reinterpret_cast<float4*>(Els + t * 4) =
        *reinterpret_cast<const float4*>(enorm + t * 4);

    // ---- stage A d in [128,256) to LDS (coalesced dword loads, b128 writes)
    const float* xbase = input + (size_t)b * (D_DIM * HW) + h0 * 64;
    {
#pragma unroll
        for (int half = 0; half < 2; ++half) {
            const int r = half * 64 + lane;
            const float* hp = xbase + half * 64 + lane;
            const int r7 = r & 7;
#pragma unroll
            for (int q = 0; q < 4; ++q) {
                const int slot = wid * 4 + q;     // 0..15
                const int d = 128 + slot * 8;
                float v[8];
#pragma unroll
                for (int j = 0; j < 8; ++j) v[j] = hp[(size_t)(d + j) * HW];
                union { _Float16 h[8]; uint4 u; } pk;
#pragma unroll
                for (int j = 0; j < 8; ++j) pk.h[j] = (_Float16)v[j];
                const int byte = r * 256 + (((slot & 8) | ((slot & 7) ^ r7)) << 4);
                *reinterpret_cast<uint4*>(Als + byte) = pk.u;
            }
        }
    }

    // ---- A d<128 directly global -> registers (this wave's 64 pos)
    half8v aR[4][4];                             // [mi][dc], dc<4
    {
        const float* xw = xbase + wm * 64;
#pragma unroll
        for (int dc = 0; dc < 4; ++dc)
#pragma unroll
            for (int mi = 0; mi < 4; ++mi) {
                const float* p = xw + (size_t)(dc * 32 + l4 * 8) * HW + mi * 16 + l15;
                float v[8];
#pragma unroll
                for (int j = 0; j < 8; ++j) v[j] = p[(size_t)j * HW];
                union { _Float16 h[8]; half8v hv; } pk;
#pragma unroll
                for (int j = 0; j < 8; ++j) pk.h[j] = (_Float16)v[j];
                aR[mi][dc] = pk.hv;
            }
    }

    asm volatile("s_waitcnt vmcnt(0) lgkmcnt(0)" ::: "memory");
    __builtin_amdgcn_s_barrier();
    __builtin_amdgcn_sched_barrier(0);

    // fragment addresses
    int aRow[4], aR7[4], bOfs[4];
#pragma unroll
    for (int mi = 0; mi < 4; ++mi) {
        int r = wm * 64 + mi * 16 + l15;         // pos row (block-local)
        aRow[mi] = (mi * 16 + l15) * 256;        // A-LDS row (128 rows = this pos set? no:)
        aR7[mi] = r & 7;
    }
    // NOTE: A-LDS holds ALL 128 pos rows; this wave reads rows wm*64+mi*16+l15.
#pragma unroll
    for (int mi = 0; mi < 4; ++mi) aRow[mi] = (wm * 64 + mi * 16 + l15) * 256;
#pragma unroll
    for (int ni = 0; ni < 4; ++ni) {
        int r = wn * 64 + ni * 16 + l15;
        bOfs[ni] = r * 64 + ((l4 ^ ((r >> 1) & 3)) << 4);
    }

    float m1[4][4], m2[4][4];
    int   i1[4][4];
#pragma unroll
    for (int mi = 0; mi < 4; ++mi)
#pragma unroll
        for (int r = 0; r < 4; ++r) { m1[mi][r] = 3.402823466e38f; m2[mi][r] = 3.402823466e38f; i1[mi][r] = 0; }

    float4v acc[4][4];

    for (int ss = 0; ss < 8; ++ss) {             // nc chunks of 128 codes
#pragma unroll
        for (int dc = 0; dc < 8; ++dc) {         // K=32 steps (compile-time dc)
            const int s = ss * 8 + dc;
            if (dc == 0) {
#pragma unroll
                for (int mi = 0; mi < 4; ++mi)
#pragma unroll
                    for (int ni = 0; ni < 4; ++ni) acc[mi][ni] = (float4v){0.f, 0.f, 0.f, 0.f};
            }
            // stage s+2 (ring slot (dc+2)&3 — compile-time)
            if (ss < 7 || dc < 6) {
                const char* src = embT + (size_t)(s + 2) * 8192 + wid * 2048 + lane * 16;
                char* dst = Bls + ((dc + 2) & 3) * 8192 + wid * 2048;
                load_lds16(src, dst);
                load_lds16(src + 1024, dst + 1024);
            }
            if (ss < 7 || dc < 6)      asm volatile("s_waitcnt vmcnt(4)" ::: "memory");
            else if (dc == 6)          asm volatile("s_waitcnt vmcnt(2)" ::: "memory");
            else                       asm volatile("s_waitcnt vmcnt(0)" ::: "memory");
            __builtin_amdgcn_s_barrier();
            __builtin_amdgcn_sched_barrier(0);

            const char* curB = Bls + (dc & 3) * 8192;
            half8v bF[4];
#pragma unroll
            for (int ni = 0; ni < 4; ++ni)
                bF[ni] = *reinterpret_cast<const half8v*>(curB + bOfs[ni]);
            half8v aU[4];
            if (dc < 4) {
#pragma unroll
                for (int mi = 0; mi < 4; ++mi) aU[mi] = aR[mi][dc];
            } else {
                const int slot = (dc - 4) * 4 + l4;
#pragma unroll
                for (int mi = 0; mi < 4; ++mi)
                    aU[mi] = *reinterpret_cast<const half8v*>(
                        Als + aRow[mi] + (((slot & 8) | ((slot & 7) ^ aR7[mi])) << 4));
            }
            __builtin_amdgcn_s_setprio(1);
#pragma unroll
            for (int mi = 0; mi < 4; ++mi)
#pragma unroll
                for (int ni = 0; ni < 4; ++ni)
                    acc[mi][ni] = __builtin_amdgcn_mfma_f32_16x16x32_f16(aU[mi], bF[ni], acc[mi][ni], 0, 0, 0);
            __builtin_amdgcn_s_setprio(0);

            if (dc == 7) {                       // epilogue for this 128-code chunk
#pragma unroll
                for (int ni = 0; ni < 4; ++ni) {
                    int code = ss * 128 + wn * 64 + ni * 16 + l15;
                    float en = Els[code];
#pragma unroll
                    for (int mi = 0; mi < 4; ++mi)
#pragma unroll
                        for (int r = 0; r < 4; ++r) {
                            float sv = fmaf(-2.f, acc[mi][ni][r], en);
                            if (sv < m1[mi][r]) { m2[mi][r] = m1[mi][r]; m1[mi][r] = sv; i1[mi][r] = code; }
                            else m2[mi][r] = fminf(m2[mi][r], sv);
                        }
                }
            }
        }
    }

    // butterfly across the 16 column-lanes (lex-min on (val, idx), keep min2)
#pragma unroll
    for (int mi = 0; mi < 4; ++mi)
#pragma unroll
        for (int r = 0; r < 4; ++r) {
            float a1 = m1[mi][r], a2 = m2[mi][r]; int ai = i1[mi][r];
#pragma unroll
            for (int m = 8; m >= 1; m >>= 1) {
                float b1 = __shfl_xor(a1, m, 64);
                float b2 = __shfl_xor(a2, m, 64);
                int   bi = __shfl_xor(ai, m, 64);
                bool take = (b1 < a1) || (b1 == a1 && bi < ai);
                float hi = take ? a1 : b1;
                a1 = take ? b1 : a1;
                ai = take ? bi : ai;
                a2 = fminf(fminf(a2, b2), hi);
            }
            m1[mi][r] = a1; m2[mi][r] = a2; i1[mi][r] = ai;
        }

    __syncthreads();                             // done with A/B/enorm; reuse LDS
    float* Lm1 = reinterpret_cast<float*>(lds);  // [2][128]
    float* Lm2 = Lm1 + 256;
    int*   Li1 = reinterpret_cast<int*>(Lm2 + 256);
    if (l15 == 0) {
#pragma unroll
        for (int mi = 0; mi < 4; ++mi)
#pragma unroll
            for (int r = 0; r < 4; ++r) {
                int pos = wm * 64 + mi * 16 + l4 * 4 + r;
                Lm1[wn * 128 + pos] = m1[mi][r];
                Lm2[wn * 128 + pos] = m2[mi][r];
                Li1[wn * 128 + pos] = i1[mi][r];
            }
    }
    __syncthreads();
    if (t < 128) {
        float a1 = Lm1[t], a2 = Lm2[t]; int ai = Li1[t];
        float b1 = Lm1[128 + t], b2 = Lm2[128 + t]; int bi = Li1[128 + t];
        bool take = (b1 < a1) || (b1 == a1 && bi < ai);
        float hi = take ? a1 : b1;
        float f1 = take ? b1 : a1;
        int   fi = take ? bi : ai;
        float f2 = fminf(fminf(a2, b2), hi);
        int n = n0 + t;
        indf[n] = (float)fi;
        if (f2 - f1 < TAU) {                     // near-tie: exact rescan later
            int slot = atomicAdd(count, 1);
            list[slot] = n;
        }
    }
}

// ---------------------------------------------------------------------------
// Kernel 3: exact fp32 rescan — 4 flagged positions per wave (unchanged).
// ---------------------------------------------------------------------------
__launch_bounds__(256, 2)
__global__ void vq_refine(const float* __restrict__ input,
                          const float* __restrict__ embed,
                          const float* __restrict__ enorm,
                          float* __restrict__ indf,
                          const int* __restrict__ count,
                          const int* __restrict__ list) {
    __shared__ float xls[4][4][D_DIM];
    const int wslot = threadIdx.x >> 6;
    const int lane  = threadIdx.x & 63;
    const int gw    = blockIdx.x * 4 + wslot;
    const int nw    = gridDim.x * 4;
    const int cnt   = *count;
    if (cnt == 0) return;
    const int ngroups = (cnt + 3) >> 2;

    const float* ep = embed + lane * 16;
    float en[16];
    {
        float4 e0 = *reinterpret_cast<const float4*>(enorm + lane * 16);
        float4 e1 = *reinterpret_cast<const float4*>(enorm + lane * 16 + 4);
        float4 e2 = *reinterpret_cast<const float4*>(enorm + lane * 16 + 8);
        float4 e3 = *reinterpret_cast<const float4*>(enorm + lane * 16 + 12);
        en[0]=e0.x; en[1]=e0.y; en[2]=e0.z; en[3]=e0.w;
        en[4]=e1.x; en[5]=e1.y; en[6]=e1.z; en[7]=e1.w;
        en[8]=e2.x; en[9]=e2.y; en[10]=e2.z; en[11]=e2.w;
        en[12]=e3.x; en[13]=e3.y; en[14]=e3.z; en[15]=e3.w;
    }

    for (int g = gw; g < ngroups; g += nw) {
        int np[4];
        const float* bp[4];
#pragma unroll
        for (int p = 0; p < 4; ++p) {
            int li = g * 4 + p; if (li >= cnt) li = cnt - 1;   // tail dup: benign
            np[p] = list[li];
            int b = np[p] >> 12, rem = np[p] & 4095;
            bp[p] = input + (size_t)b * (D_DIM * HW) + rem;
        }
#pragma unroll
        for (int j = 0; j < 16; ++j) {
            int p = j >> 2;
            int d = (j & 3) * 64 + lane;
            xls[wslot][p][d] = bp[p][(size_t)d * HW];
        }
        asm volatile("s_waitcnt lgkmcnt(0)" ::: "memory");
        __builtin_amdgcn_sched_barrier(0);

        float acc[4][16];
#pragma unroll
        for (int p = 0; p < 4; ++p)
#pragma unroll
            for (int j = 0; j < 16; ++j) acc[p][j] = 0.f;

#pragma unroll 2
        for (int d = 0; d < D_DIM; ++d) {
            const float* er = ep + (size_t)d * K_CODES;
            float4 e0 = *reinterpret_cast<const float4*>(er);
            float4 e1 = *reinterpret_cast<const float4*>(er + 4);
            float4 e2 = *reinterpret_cast<const float4*>(er + 8);
            float4 e3 = *reinterpret_cast<const float4*>(er + 12);
            float ea[16] = {e0.x, e0.y, e0.z, e0.w, e1.x, e1.y, e1.z, e1.w,
                            e2.x, e2.y, e2.z, e2.w, e3.x, e3.y, e3.z, e3.w};
            float xd[4] = {xls[wslot][0][d], xls[wslot][1][d],
                           xls[wslot][2][d], xls[wslot][3][d]};
#pragma unroll
            for (int p = 0; p < 4; ++p)
#pragma unroll
                for (int j = 0; j < 16; ++j)
                    acc[p][j] = fmaf(xd[p], ea[j], acc[p][j]);
        }

#pragma unroll
        for (int p = 0; p < 4; ++p) {
            float bs = 3.402823466e38f; int bk = 0;
#pragma unroll
            for (int j = 0; j < 16; ++j) {
                float s = fmaf(-2.f, acc[p][j], en[j]);
                if (s < bs) { bs = s; bk = lane * 16 + j; }
            }
#pragma unroll
            for (int m = 32; m >= 1; m >>= 1) {
                float os = __shfl_xor(bs, m, 64);
                int   ok = __shfl_xor(bk, m, 64);
                if (os < bs || (os == bs && ok < bk)) { bs = os; bk = ok; }
            }
            if (lane == 0) indf[np[p]] = (float)bk;
        }
        __syncthreads();
    }
}

// ---------------------------------------------------------------------------
// Kernel 4: gather outputs (overwrites the scratch regions last)
// ---------------------------------------------------------------------------
__global__ void vq_gather(const float* __restrict__ embed,
                          const float* __restrict__ indf,
                          float* __restrict__ out0,
                          float* __restrict__ out1) {
    int gid = blockIdx.x * 256 + threadIdx.x;    // BDHW/4 threads
    int w4   = (gid & 15) * 4;
    int rest = gid >> 4;
    int h  = rest & 63;
    int bd = rest >> 6;
    int d  = bd & 255;
    int b  = bd >> 8;
    int n  = (b * 64 + h) * 64 + w4;
    float4 fi = *reinterpret_cast<const float4*>(indf + n);
    const float* erow = embed + (size_t)d * K_CODES;
    float4 q;
    q.x = erow[(int)fi.x];
    q.y = erow[(int)fi.y];
    q.z = erow[(int)fi.z];
    q.w = erow[(int)fi.w];
    size_t o = (size_t)gid * 4;
    *reinterpret_cast<float4*>(out0 + o) = q;
    *reinterpret_cast<float4*>(out1 + o) = q;
}

// ---------------------------------------------------------------------------
extern "C" void kernel_launch(void* const* d_in, const int* in_sizes, int n_in,
                              void* d_out, int out_size, void* d_ws, size_t ws_size,
                              hipStream_t stream) {
    const float* input = (const float*)d_in[0];  // [32, 256, 64, 64] f32
    const float* embed = (const float*)d_in[1];  // [256, 1024] f32
    float* out0 = (float*)d_out;
    float* out1 = out0 + (size_t)BDHW;
    float* indf = out0 + (size_t)2 * BDHW;

    // scratch inside d_out (overwritten by vq_gather at the end):
    uint4* embT  = (uint4*)out0;                 // 512 KB pre-swizzled f16 chunks
    float* enorm = out0 + 131072;                // 4 KB (right after embT)
    int* count = (int*)out1;
    int* list  = (int*)out1 + 1;

    vq_prep  <<<64,          256, 0, stream>>>(embed, embT);
    vq_enorm <<<8,           256, 0, stream>>>(embed, enorm, count);
    vq_argmin<<<N_POS / 128, 256, 0, stream>>>(input, (const char*)embT, enorm, indf, count, list);
    vq_refine<<<256,         256, 0, stream>>>(input, embed, enorm, indf, count, list);
    vq_gather<<<BDHW / 1024, 256, 0, stream>>>(embed, indf, out0, out1);
}